// Round 6
// baseline (345.057 us; speedup 1.0000x reference)
//
#include <hip/hip_runtime.h>
#include <math.h>

#define CAP 64   // bucket capacity per node; Poisson(16) max ~45 whp

typedef __attribute__((ext_vector_type(8))) short bf16x8;
typedef __attribute__((ext_vector_type(4))) float f32x4;

__device__ __forceinline__ unsigned short f2bf(float x) {  // RTN-even f32->bf16
  unsigned u = __float_as_uint(x);
  return (unsigned short)((u + 0x7fffu + ((u >> 16) & 1u)) >> 16);
}
__device__ __forceinline__ float bf2f(unsigned short h) {
  return __uint_as_float(((unsigned)h) << 16);
}

// ---------------- build per-dst bucket lists ----------------
__global__ __launch_bounds__(256) void k_build(const int* __restrict__ ei,
                                               int* __restrict__ cnt,
                                               int* __restrict__ bucket, int E) {
  int e = blockIdx.x * 256 + threadIdx.x;
  if (e >= E) return;
  int s = ei[e];
  int d = ei[E + e];
  int pos = atomicAdd(&cnt[d], 1);
  if (pos < CAP) bucket[(size_t)d * CAP + pos] = s;
}

__global__ __launch_bounds__(256) void k_dinv(const int* __restrict__ cnt,
                                              float* __restrict__ dinv, int n) {
  int i = blockIdx.x * 256 + threadIdx.x;
  if (i < n) dinv[i] = rsqrtf((float)(cnt[i] + 1));
}

// ---------------- weight prep: split f32 W[K][N] -> bf16 hi/lo, transposed [N][K] ---
__global__ __launch_bounds__(256) void k_wsplit(const float* __restrict__ W,
                                                unsigned short* __restrict__ Wh,
                                                unsigned short* __restrict__ Wl,
                                                int K, int N) {
  int i = blockIdx.x * 256 + threadIdx.x;
  if (i >= K * N) return;
  int k = i / N, c = i - k * N;
  float x = W[i];
  unsigned short h = f2bf(x);
  unsigned short l = f2bf(x - bf2f(h));
  Wh[(size_t)c * K + k] = h;
  Wl[(size_t)c * K + k] = l;
}

// ---------------- MFMA split-bf16 GEMM: out[M,128] = (A @ W)*dinv[row] ---------
template <int K>
__global__ __launch_bounds__(256, 2) void k_gemm128_mfma(
    const float* __restrict__ A, const unsigned short* __restrict__ Bhg,
    const unsigned short* __restrict__ Blg, const float* __restrict__ dinv,
    float* __restrict__ out, int M) {
  __shared__ unsigned short Ah[64][72], Al[64][72];    // [row][k], pitch 144B
  __shared__ unsigned short Bh[128][72], Bl[128][72];  // [col][k]
  const int t = threadIdx.x;
  const int bm = blockIdx.x * 64;
  const int wv = t >> 6, la = t & 63;
  const int wr = (wv >> 1) * 32;   // wave row base: 0 / 32
  const int wc = (wv & 1) * 64;    // wave col base: 0 / 64
  const int ra = la & 15;          // frag row/col within 16
  const int rq = la >> 4;          // k-group 0..3

  f32x4 acc[2][4];
#pragma unroll
  for (int i = 0; i < 2; ++i)
#pragma unroll
    for (int j = 0; j < 4; ++j) acc[i][j] = (f32x4){0.f, 0.f, 0.f, 0.f};

  for (int k0 = 0; k0 < K; k0 += 64) {
#pragma unroll
    for (int l = 0; l < 4; ++l) {
      int idx = l * 256 + t;
      int r = idx >> 4, c4 = (idx & 15) * 4;
      int gr = bm + r;
      float4 v = make_float4(0.f, 0.f, 0.f, 0.f);
      if (gr < M) v = *(const float4*)(A + (size_t)gr * K + k0 + c4);
      unsigned short h0 = f2bf(v.x), h1 = f2bf(v.y), h2 = f2bf(v.z), h3 = f2bf(v.w);
      unsigned short q0 = f2bf(v.x - bf2f(h0)), q1 = f2bf(v.y - bf2f(h1));
      unsigned short q2 = f2bf(v.z - bf2f(h2)), q3 = f2bf(v.w - bf2f(h3));
      *(ushort4*)&Ah[r][c4] = make_ushort4(h0, h1, h2, h3);
      *(ushort4*)&Al[r][c4] = make_ushort4(q0, q1, q2, q3);
    }
#pragma unroll
    for (int l = 0; l < 4; ++l) {
      int idx = l * 256 + t;
      int c = idx >> 3, k8 = (idx & 7) * 8;
      *(bf16x8*)&Bh[c][k8] = *(const bf16x8*)(Bhg + (size_t)c * K + k0 + k8);
      *(bf16x8*)&Bl[c][k8] = *(const bf16x8*)(Blg + (size_t)c * K + k0 + k8);
    }
    __syncthreads();
#pragma unroll
    for (int ks = 0; ks < 2; ++ks) {
      const int ko = ks * 32 + rq * 8;
      bf16x8 a_h[2], a_l[2], b_h[4], b_l[4];
#pragma unroll
      for (int i = 0; i < 2; ++i) {
        a_h[i] = *(const bf16x8*)&Ah[wr + i * 16 + ra][ko];
        a_l[i] = *(const bf16x8*)&Al[wr + i * 16 + ra][ko];
      }
#pragma unroll
      for (int j = 0; j < 4; ++j) {
        b_h[j] = *(const bf16x8*)&Bh[wc + j * 16 + ra][ko];
        b_l[j] = *(const bf16x8*)&Bl[wc + j * 16 + ra][ko];
      }
#pragma unroll
      for (int i = 0; i < 2; ++i)
#pragma unroll
        for (int j = 0; j < 4; ++j) {
          acc[i][j] = __builtin_amdgcn_mfma_f32_16x16x32_bf16(a_h[i], b_h[j], acc[i][j], 0, 0, 0);
          acc[i][j] = __builtin_amdgcn_mfma_f32_16x16x32_bf16(a_h[i], b_l[j], acc[i][j], 0, 0, 0);
          acc[i][j] = __builtin_amdgcn_mfma_f32_16x16x32_bf16(a_l[i], b_h[j], acc[i][j], 0, 0, 0);
        }
    }
    __syncthreads();
  }
#pragma unroll
  for (int i = 0; i < 2; ++i)
#pragma unroll
    for (int r = 0; r < 4; ++r) {
      int row = bm + wr + i * 16 + rq * 4 + r;
      if (row < M) {
        float d = dinv[row];
#pragma unroll
        for (int j = 0; j < 4; ++j)
          out[(size_t)row * 128 + wc + j * 16 + ra] = acc[i][j][r] * d;
      }
    }
}

// ---------------- SGEMM K=128 -> N=40: 256 thr, 128x40 tile, 4x5/thread --------
__global__ __launch_bounds__(256, 2) void k_gemm40(const float* __restrict__ A,
                                                   const float* __restrict__ W,
                                                   const float* __restrict__ dinv,
                                                   float* __restrict__ out, int M) {
  __shared__ float xs[32][132];
  __shared__ float wt[40][36];
  const int t = threadIdx.x;
  const int bm = blockIdx.x * 128;
  const int tr = t >> 3;
  const int tc = t & 7;
  float acc[4][5] = {};
  for (int k0 = 0; k0 < 128; k0 += 32) {
#pragma unroll
    for (int l = 0; l < 4; ++l) {
      int idx = l * 256 + t;
      int r = idx & 127, c4 = (idx >> 7) * 4;
      int gr = bm + r;
      float4 v = make_float4(0.f, 0.f, 0.f, 0.f);
      if (gr < M) v = *(const float4*)(A + (size_t)gr * 128 + k0 + c4);
      xs[c4 + 0][r] = v.x; xs[c4 + 1][r] = v.y;
      xs[c4 + 2][r] = v.z; xs[c4 + 3][r] = v.w;
    }
#pragma unroll
    for (int u = 0; u < 5; ++u) {
      int idx = u * 256 + t;
      if (idx < 32 * 40) {
        int kr = idx / 40, c = idx - kr * 40;
        wt[c][kr] = W[(size_t)(k0 + kr) * 40 + c];
      }
    }
    __syncthreads();
#pragma unroll
    for (int kq = 0; kq < 8; ++kq) {
      float a_[4][4];
      float b_[5][4];
#pragma unroll
      for (int kk = 0; kk < 4; ++kk)
        *(float4*)&a_[kk][0] = *(const float4*)&xs[kq * 4 + kk][tr * 4];
#pragma unroll
      for (int j = 0; j < 5; ++j)
        *(float4*)&b_[j][0] = *(const float4*)&wt[tc * 5 + j][kq * 4];
#pragma unroll
      for (int kk = 0; kk < 4; ++kk)
#pragma unroll
        for (int i = 0; i < 4; ++i)
#pragma unroll
          for (int j = 0; j < 5; ++j) acc[i][j] += a_[kk][i] * b_[j][kk];
    }
    __syncthreads();
  }
#pragma unroll
  for (int i = 0; i < 4; ++i) {
    int r = bm + tr * 4 + i;
    if (r >= M) continue;
    float d = dinv[r];
#pragma unroll
    for (int j = 0; j < 5; ++j) out[(size_t)r * 40 + tc * 5 + j] = acc[i][j] * d;
  }
}

// -------- aggregation F=128, XCD column-sliced: chunk = blockIdx%8 -> 16 cols --------
// Each XCD's blocks all process the same 16-col slice of g (3.2 MB, L2-resident).
// 16-lane group per node; bucket row preloaded as guarded int4/lane, shfl-distributed.
__global__ __launch_bounds__(256) void k_agg128s(const float* __restrict__ g,
                                                 const int* __restrict__ bucket,
                                                 const int* __restrict__ cnt,
                                                 const float* __restrict__ dinv,
                                                 const float* __restrict__ bias,
                                                 float* __restrict__ out, int n) {
  const int t = threadIdx.x;
  const int chunk = blockIdx.x & 7;   // same-XCD blocks share a column chunk
  const int nb = blockIdx.x >> 3;
  const int lane = t & 63;
  const int gi = (t >> 6) * 4 + (lane >> 4);  // group 0..15 within block
  const int sub = lane & 15;
  const int gb = lane & 48;                   // group base lane within wave
  const int node = nb * 16 + gi;
  if (node >= n) return;
  const int col = chunk * 16 + sub;
  const int c = min(cnt[node], CAP);
  const float di = dinv[node];
  int i0 = 0, i1 = 0, i2 = 0, i3 = 0;
  if (sub * 4 < c) {  // only touch bucket lines that hold real edges
    int4 v = *(const int4*)(bucket + (size_t)node * CAP + sub * 4);
    i0 = v.x; i1 = v.y; i2 = v.z; i3 = v.w;
  }
  float a0 = g[(size_t)node * 128 + col];  // self loop
  float a1 = 0.f, a2 = 0.f, a3 = 0.f;
  const int n4 = (c + 3) >> 2;
  for (int q = 0; q < n4; ++q) {
    int s0 = __shfl(i0, gb + q);
    int s1 = __shfl(i1, gb + q);
    int s2 = __shfl(i2, gb + q);
    int s3 = __shfl(i3, gb + q);
    int e = q * 4;
    a0 += g[(size_t)s0 * 128 + col];                    // e < c guaranteed
    if (e + 1 < c) a1 += g[(size_t)s1 * 128 + col];
    if (e + 2 < c) a2 += g[(size_t)s2 * 128 + col];
    if (e + 3 < c) a3 += g[(size_t)s3 * 128 + col];
  }
  out[(size_t)node * 128 + col] = ((a0 + a1) + (a2 + a3)) * di + bias[col];
}

// ---------------- aggregation: wave per node, F=40, unroll 8 ----------------
__global__ __launch_bounds__(256) void k_agg40(const float* __restrict__ g,
                                               const int* __restrict__ bucket,
                                               const int* __restrict__ cnt,
                                               const float* __restrict__ dinv,
                                               const float* __restrict__ bias,
                                               float* __restrict__ out, int n) {
  int wid = (blockIdx.x * 256 + threadIdx.x) >> 6;
  int lane = threadIdx.x & 63;
  if (wid >= n) return;
  int le = lane < 40 ? lane : 0;
  int c = min(cnt[wid], CAP);
  float di = dinv[wid];
  int idx = bucket[(size_t)wid * CAP + lane];
  float a[8];
  a[0] = g[(size_t)wid * 40 + le];
#pragma unroll
  for (int u = 1; u < 8; ++u) a[u] = 0.f;
  for (int e = 0; e < c; e += 8) {
#pragma unroll
    for (int u = 0; u < 8; ++u) {
      int valid = (e + u) < c;
      int s = __shfl(idx, e + u);
      s = valid ? s : wid;
      float m = valid ? 1.f : 0.f;
      a[u] = fmaf(g[(size_t)s * 40 + le], m, a[u]);
    }
  }
  float sa = ((a[0] + a[1]) + (a[2] + a[3])) + ((a[4] + a[5]) + (a[6] + a[7]));
  if (lane < 40) out[(size_t)wid * 40 + lane] = sa * di + bias[lane];
}

extern "C" void kernel_launch(void* const* d_in, const int* in_sizes, int n_in,
                              void* d_out, int out_size, void* d_ws, size_t ws_size,
                              hipStream_t stream) {
  const float* x  = (const float*)d_in[0];
  const int*   ei = (const int*)d_in[1];
  const float* W1 = (const float*)d_in[2];
  const float* b1 = (const float*)d_in[3];
  const float* W2 = (const float*)d_in[4];
  const float* b2 = (const float*)d_in[5];
  const float* W3 = (const float*)d_in[6];
  const float* b3 = (const float*)d_in[7];
  float* out = (float*)d_out;

  const int n = in_sizes[0] / 256;  // 50000
  const int E = in_sizes[1] / 2;    // 800000

  char* ws = (char*)d_ws;
  int*   cnt    = (int*)(ws + 0);                       // 200 KB
  float* dinv   = (float*)(ws + (1ll << 20));           // 200 KB
  int*   bucket = (int*)(ws + (2ll << 20));             // 12.8 MB
  unsigned short* W1h = (unsigned short*)(ws + (15ll << 20));              // 64 KB
  unsigned short* W1l = (unsigned short*)(ws + (15ll << 20) + (64 << 10)); // 64 KB
  unsigned short* W2h = (unsigned short*)(ws + (15ll << 20) + (128 << 10));// 32 KB
  unsigned short* W2l = (unsigned short*)(ws + (15ll << 20) + (160 << 10));// 32 KB
  float* bufA   = (float*)(ws + (16ll << 20));          // 25.6 MB
  float* bufB   = (float*)(ws + (42ll << 20));          // 25.6 MB

  hipMemsetAsync(cnt, 0, n * sizeof(int), stream);
  k_build<<<(E + 255) / 256, 256, 0, stream>>>(ei, cnt, bucket, E);
  k_dinv<<<(n + 255) / 256, 256, 0, stream>>>(cnt, dinv, n);
  k_wsplit<<<(256 * 128 + 255) / 256, 256, 0, stream>>>(W1, W1h, W1l, 256, 128);
  k_wsplit<<<(128 * 128 + 255) / 256, 256, 0, stream>>>(W2, W2h, W2l, 128, 128);

  int gb64  = (n + 63) / 64;            // 782 blocks for gemm128_mfma
  int gb128 = (n + 127) / 128;          // 392 blocks for gemm40
  int asb = ((n + 15) / 16) * 8;        // 25000 blocks: 16 nodes x 8 col-chunks
  int ab  = (n * 64 + 255) / 256;       // one wave per node (agg40)

  // layer 1: g1 = (x @ W1) * dinv ; h1 = dinv*(g1[i]+sum g1[src]) + b1
  k_gemm128_mfma<256><<<gb64, 256, 0, stream>>>(x, W1h, W1l, dinv, bufA, n);
  k_agg128s<<<asb, 256, 0, stream>>>(bufA, bucket, cnt, dinv, b1, bufB, n);
  // layer 2
  k_gemm128_mfma<128><<<gb64, 256, 0, stream>>>(bufB, W2h, W2l, dinv, bufA, n);
  k_agg128s<<<asb, 256, 0, stream>>>(bufA, bucket, cnt, dinv, b2, bufB, n);
  // layer 3
  k_gemm40<<<gb128, 256, 0, stream>>>(bufB, W3, dinv, bufA, n);
  k_agg40<<<ab, 256, 0, stream>>>(bufA, bucket, cnt, dinv, b3, out, n);
}

// Round 7
// 234.393 us; speedup vs baseline: 1.4721x; 1.4721x over previous
//
#include <hip/hip_runtime.h>
#include <math.h>

#define CAP 64   // bucket capacity per node; Poisson(16) max ~45 whp

typedef __attribute__((ext_vector_type(8))) short bf16x8;
typedef __attribute__((ext_vector_type(4))) float f32x4;

__device__ __forceinline__ unsigned short f2bf(float x) {  // RTN-even f32->bf16
  unsigned u = __float_as_uint(x);
  return (unsigned short)((u + 0x7fffu + ((u >> 16) & 1u)) >> 16);
}
__device__ __forceinline__ float bf2f(unsigned short h) {
  return __uint_as_float(((unsigned)h) << 16);
}

// ---------------- build per-dst bucket lists ----------------
__global__ __launch_bounds__(256) void k_build(const int* __restrict__ ei,
                                               int* __restrict__ cnt,
                                               int* __restrict__ bucket, int E) {
  int e = blockIdx.x * 256 + threadIdx.x;
  if (e >= E) return;
  int s = ei[e];
  int d = ei[E + e];
  int pos = atomicAdd(&cnt[d], 1);
  if (pos < CAP) bucket[(size_t)d * CAP + pos] = s;
}

__global__ __launch_bounds__(256) void k_dinv(const int* __restrict__ cnt,
                                              float* __restrict__ dinv, int n) {
  int i = blockIdx.x * 256 + threadIdx.x;
  if (i < n) dinv[i] = rsqrtf((float)(cnt[i] + 1));
}

// ---- aggvec: outv[i] = dinv[i] * (in[i] + sum_{src in in(i)} in[src]) --------
// in is tiny (200 KB, L2-resident). Lane-parallel gather + wave reduction.
__global__ __launch_bounds__(256) void k_aggvec(const float* __restrict__ in,
                                                float* __restrict__ outv,
                                                const int* __restrict__ bucket,
                                                const int* __restrict__ cnt,
                                                const float* __restrict__ dinv,
                                                int n) {
  int wid = (blockIdx.x * 256 + threadIdx.x) >> 6;
  int lane = threadIdx.x & 63;
  if (wid >= n) return;
  int c = min(cnt[wid], CAP);
  float v = 0.f;
  if (lane < c) v = in[bucket[(size_t)wid * CAP + lane]];
#pragma unroll
  for (int off = 32; off; off >>= 1) v += __shfl_xor(v, off);
  if (lane == 0) outv[wid] = dinv[wid] * (in[wid] + v);
}

// ---------------- tiny f32 matmul: C[M][N] = A[M][K] @ B[K][N] ----------------
__global__ __launch_bounds__(256) void k_mm_f32(const float* __restrict__ A,
                                                const float* __restrict__ B,
                                                float* __restrict__ C,
                                                int M, int K, int N) {
  int i = blockIdx.x * 256 + threadIdx.x;
  if (i >= M * N) return;
  int r = i / N, c = i - r * N;
  float s = 0.f;
  for (int k = 0; k < K; ++k) s += A[(size_t)r * K + k] * B[(size_t)k * N + c];
  C[i] = s;
}

// ---- split W123[K=256][40] -> bf16 hi/lo transposed+padded [48][256] ---------
__global__ __launch_bounds__(256) void k_wsplit_t(const float* __restrict__ W,
                                                  unsigned short* __restrict__ Wh,
                                                  unsigned short* __restrict__ Wl) {
  int i = blockIdx.x * 256 + threadIdx.x;
  if (i >= 48 * 256) return;
  int c = i >> 8, k = i & 255;
  float x = (c < 40) ? W[(size_t)k * 40 + c] : 0.f;
  unsigned short h = f2bf(x);
  unsigned short l = f2bf(x - bf2f(h));
  Wh[i] = h;
  Wl[i] = l;
}

// ---- bias prep: v1 = b1^T W2 W3 (40), v2 = b2^T W3 (40) ----------------------
__global__ __launch_bounds__(256) void k_bias_prep(const float* __restrict__ b1,
                                                   const float* __restrict__ W2,
                                                   const float* __restrict__ W3,
                                                   const float* __restrict__ b2,
                                                   float* __restrict__ v1,
                                                   float* __restrict__ v2) {
  __shared__ float w2b[128];
  int t = threadIdx.x;
  if (t < 128) {
    float s = 0.f;
    for (int k = 0; k < 128; ++k) s += b1[k] * W2[(size_t)k * 128 + t];
    w2b[t] = s;
  }
  __syncthreads();
  if (t < 40) {
    float s1 = 0.f, s2 = 0.f;
    for (int j = 0; j < 128; ++j) {
      float w = W3[(size_t)j * 40 + t];
      s1 += w2b[j] * w;
      s2 += b2[j] * w;
    }
    v1[t] = s1;
    v2[t] = s2;
  }
}

// ---- MFMA split-bf16 GEMM: Z[M][40] = dinv[row] * (X[M][256] @ W123) ---------
// 256 thr = 4 waves; tile 64 rows x 48 cols (40 used); BK=64; bf16x3 products.
__global__ __launch_bounds__(256, 2) void k_zgemm(const float* __restrict__ X,
                                                  const unsigned short* __restrict__ Bhg,
                                                  const unsigned short* __restrict__ Blg,
                                                  const float* __restrict__ dinv,
                                                  float* __restrict__ Z, int M) {
  __shared__ unsigned short Ah[64][72], Al[64][72];  // [row][k]
  __shared__ unsigned short Bh[48][72], Bl[48][72];  // [col][k]
  const int t = threadIdx.x;
  const int bm = blockIdx.x * 64;
  const int wv = t >> 6, la = t & 63;
  const int ra = la & 15;  // row/col within 16x16 frag
  const int rq = la >> 4;  // k-group 0..3

  f32x4 acc[3];
#pragma unroll
  for (int j = 0; j < 3; ++j) acc[j] = (f32x4){0.f, 0.f, 0.f, 0.f};

  for (int k0 = 0; k0 < 256; k0 += 64) {
    // stage A 64x64 f32 -> split hi/lo bf16
#pragma unroll
    for (int l = 0; l < 4; ++l) {
      int idx = l * 256 + t;
      int r = idx >> 4, c4 = (idx & 15) * 4;
      int gr = bm + r;
      float4 v = make_float4(0.f, 0.f, 0.f, 0.f);
      if (gr < M) v = *(const float4*)(X + (size_t)gr * 256 + k0 + c4);
      unsigned short h0 = f2bf(v.x), h1 = f2bf(v.y), h2 = f2bf(v.z), h3 = f2bf(v.w);
      unsigned short q0 = f2bf(v.x - bf2f(h0)), q1 = f2bf(v.y - bf2f(h1));
      unsigned short q2 = f2bf(v.z - bf2f(h2)), q3 = f2bf(v.w - bf2f(h3));
      *(ushort4*)&Ah[r][c4] = make_ushort4(h0, h1, h2, h3);
      *(ushort4*)&Al[r][c4] = make_ushort4(q0, q1, q2, q3);
    }
    // stage W tiles (pre-split, transposed [48][256]): 48 cols x 64 k
#pragma unroll
    for (int l = 0; l < 2; ++l) {
      int idx = l * 256 + t;
      if (idx < 48 * 8) {
        int c = idx >> 3, k8 = (idx & 7) * 8;
        *(bf16x8*)&Bh[c][k8] = *(const bf16x8*)(Bhg + (size_t)c * 256 + k0 + k8);
        *(bf16x8*)&Bl[c][k8] = *(const bf16x8*)(Blg + (size_t)c * 256 + k0 + k8);
      }
    }
    __syncthreads();
#pragma unroll
    for (int ks = 0; ks < 2; ++ks) {
      const int ko = ks * 32 + rq * 8;
      bf16x8 a_h = *(const bf16x8*)&Ah[wv * 16 + ra][ko];
      bf16x8 a_l = *(const bf16x8*)&Al[wv * 16 + ra][ko];
#pragma unroll
      for (int j = 0; j < 3; ++j) {
        bf16x8 b_h = *(const bf16x8*)&Bh[j * 16 + ra][ko];
        bf16x8 b_l = *(const bf16x8*)&Bl[j * 16 + ra][ko];
        acc[j] = __builtin_amdgcn_mfma_f32_16x16x32_bf16(a_h, b_h, acc[j], 0, 0, 0);
        acc[j] = __builtin_amdgcn_mfma_f32_16x16x32_bf16(a_h, b_l, acc[j], 0, 0, 0);
        acc[j] = __builtin_amdgcn_mfma_f32_16x16x32_bf16(a_l, b_h, acc[j], 0, 0, 0);
      }
    }
    __syncthreads();
  }
  // D layout: col = la&15, row = (la>>4)*4 + r  [m89-verified]
#pragma unroll
  for (int j = 0; j < 3; ++j)
#pragma unroll
    for (int r = 0; r < 4; ++r) {
      int row = bm + wv * 16 + rq * 4 + r;
      int col = j * 16 + ra;
      if (row < M && col < 40)
        Z[(size_t)row * 40 + col] = acc[j][r] * dinv[row];
    }
}

// ---- aggregation pass, F=40 (wave per node, unroll 8) ------------------------
// s = in[i] + sum_src in[src]   (input already carries a leading dinv scale)
// FINAL=0: out = dinv^2 * s   (folds the next pass's leading dinv)
// FINAL=1: out = dinv * s + u2[i]*v1[col] + u1[i]*v2[col] + b3[col]
template <int FINAL>
__global__ __launch_bounds__(256) void k_agg40x(const float* __restrict__ in,
                                                float* __restrict__ out,
                                                const int* __restrict__ bucket,
                                                const int* __restrict__ cnt,
                                                const float* __restrict__ dinv,
                                                const float* __restrict__ u1,
                                                const float* __restrict__ u2,
                                                const float* __restrict__ v1,
                                                const float* __restrict__ v2,
                                                const float* __restrict__ b3,
                                                int n) {
  int wid = (blockIdx.x * 256 + threadIdx.x) >> 6;
  int lane = threadIdx.x & 63;
  if (wid >= n) return;
  int le = lane < 40 ? lane : 0;
  int c = min(cnt[wid], CAP);
  float di = dinv[wid];
  int idx = (lane < c) ? bucket[(size_t)wid * CAP + lane] : 0;
  float a[8];
  a[0] = in[(size_t)wid * 40 + le];  // self loop
#pragma unroll
  for (int u = 1; u < 8; ++u) a[u] = 0.f;
  for (int e = 0; e < c; e += 8) {
#pragma unroll
    for (int u = 0; u < 8; ++u) {
      int valid = (e + u) < c;
      int s = __shfl(idx, e + u);
      s = valid ? s : wid;
      float m = valid ? 1.f : 0.f;
      a[u] = fmaf(in[(size_t)s * 40 + le], m, a[u]);
    }
  }
  float sa = ((a[0] + a[1]) + (a[2] + a[3])) + ((a[4] + a[5]) + (a[6] + a[7]));
  if (lane < 40) {
    if (FINAL) {
      out[(size_t)wid * 40 + lane] =
          sa * di + u2[wid] * v1[lane] + u1[wid] * v2[lane] + b3[lane];
    } else {
      out[(size_t)wid * 40 + lane] = sa * di * di;
    }
  }
}

extern "C" void kernel_launch(void* const* d_in, const int* in_sizes, int n_in,
                              void* d_out, int out_size, void* d_ws, size_t ws_size,
                              hipStream_t stream) {
  const float* x  = (const float*)d_in[0];
  const int*   ei = (const int*)d_in[1];
  const float* W1 = (const float*)d_in[2];
  const float* b1 = (const float*)d_in[3];
  const float* W2 = (const float*)d_in[4];
  const float* b2 = (const float*)d_in[5];
  const float* W3 = (const float*)d_in[6];
  const float* b3 = (const float*)d_in[7];
  float* out = (float*)d_out;

  const int n = in_sizes[0] / 256;  // 50000
  const int E = in_sizes[1] / 2;    // 800000

  char* ws = (char*)d_ws;
  int*   cnt    = (int*)(ws + 0);                        // 200 KB
  float* dinv   = (float*)(ws + (1ll << 20));            // 200 KB
  int*   bucket = (int*)(ws + (2ll << 20));              // 12.8 MB
  float* u1     = (float*)(ws + (15ll << 20));           // 200 KB
  float* u2     = (float*)(ws + (15ll << 20) + (256 << 10));
  float* W12    = (float*)(ws + (15ll << 20) + (512 << 10));  // 128 KB
  float* W123   = (float*)(ws + (15ll << 20) + (704 << 10));  // 40 KB
  unsigned short* Wh = (unsigned short*)(ws + (15ll << 20) + (768 << 10));  // 24 KB
  unsigned short* Wl = (unsigned short*)(ws + (15ll << 20) + (800 << 10));  // 24 KB
  float* v1     = (float*)(ws + (15ll << 20) + (832 << 10));
  float* v2     = (float*)(ws + (15ll << 20) + (836 << 10));
  float* bufA   = (float*)(ws + (16ll << 20));           // 8 MB
  float* bufB   = (float*)(ws + (26ll << 20));           // 8 MB

  hipMemsetAsync(cnt, 0, n * sizeof(int), stream);
  k_build<<<(E + 255) / 256, 256, 0, stream>>>(ei, cnt, bucket, E);
  k_dinv<<<(n + 255) / 256, 256, 0, stream>>>(cnt, dinv, n);

  int ab = (n * 64 + 255) / 256;  // one wave per node
  // u1 = S*1, u2 = S^2*1  (dinv/u1 are L2-resident vectors)
  k_aggvec<<<ab, 256, 0, stream>>>(dinv, u1, bucket, cnt, dinv, n);
  k_aggvec<<<ab, 256, 0, stream>>>(u1, u2, bucket, cnt, dinv, n);

  // W123 = W1@W2@W3; split to bf16 hi/lo transposed [48][256]
  k_mm_f32<<<(256 * 128 + 255) / 256, 256, 0, stream>>>(W1, W2, W12, 256, 128, 128);
  k_mm_f32<<<(256 * 40 + 255) / 256, 256, 0, stream>>>(W12, W3, W123, 256, 128, 40);
  k_wsplit_t<<<(48 * 256 + 255) / 256, 256, 0, stream>>>(W123, Wh, Wl);
  k_bias_prep<<<1, 256, 0, stream>>>(b1, W2, W3, b2, v1, v2);

  // Z = dinv * (X @ W123)
  k_zgemm<<<(n + 63) / 64, 256, 0, stream>>>(x, Wh, Wl, dinv, bufA, n);

  // out = S^3 Z + u2 v1^T + u1 v2^T + 1 b3^T
  k_agg40x<0><<<ab, 256, 0, stream>>>(bufA, bufB, bucket, cnt, dinv, u1, u2, v1, v2, b3, n);
  k_agg40x<0><<<ab, 256, 0, stream>>>(bufB, bufA, bucket, cnt, dinv, u1, u2, v1, v2, b3, n);
  k_agg40x<1><<<ab, 256, 0, stream>>>(bufA, out, bucket, cnt, dinv, u1, u2, v1, v2, b3, n);
}

// Round 8
// 214.914 us; speedup vs baseline: 1.6056x; 1.0906x over previous
//
#include <hip/hip_runtime.h>
#include <math.h>

#define CAP 64      // bucket capacity per node; Poisson(16) max ~45 whp
#define NPART 196   // ceil(50000/256) partitions of 256 dst nodes
#define PSTRIDE 4608  // per-partition edge capacity (mean 4096 + 8 sigma)

typedef __attribute__((ext_vector_type(8))) short bf16x8;
typedef __attribute__((ext_vector_type(4))) float f32x4;

__device__ __forceinline__ unsigned short f2bf(float x) {  // RTN-even f32->bf16
  unsigned u = __float_as_uint(x);
  return (unsigned short)((u + 0x7fffu + ((u >> 16) & 1u)) >> 16);
}
__device__ __forceinline__ float bf2f(unsigned short h) {
  return __uint_as_float(((unsigned)h) << 16);
}

// ---- pass 1: partition edges by dst>>8, packed (dstlow<<17)|src ---------------
__global__ __launch_bounds__(256) void k_part1(const int* __restrict__ ei,
                                               int* __restrict__ pcnt,
                                               unsigned* __restrict__ pdata, int E) {
  __shared__ int gc[NPART];
  __shared__ int gb[NPART];
  const int t = threadIdx.x;
  const int base = blockIdx.x * 4096;
  for (int i = t; i < NPART; i += 256) gc[i] = 0;
  __syncthreads();
#pragma unroll 4
  for (int l = 0; l < 16; ++l) {
    int e = base + l * 256 + t;
    if (e < E) atomicAdd(&gc[ei[E + e] >> 8], 1);
  }
  __syncthreads();
  for (int i = t; i < NPART; i += 256) {
    gb[i] = atomicAdd(&pcnt[i], gc[i]);  // reserve contiguous range
    gc[i] = 0;
  }
  __syncthreads();
#pragma unroll 4
  for (int l = 0; l < 16; ++l) {
    int e = base + l * 256 + t;
    if (e < E) {
      int d = ei[E + e];
      int s = ei[e];
      int g = d >> 8;
      int pos = gb[g] + atomicAdd(&gc[g], 1);
      if (pos < PSTRIDE)
        pdata[(size_t)g * PSTRIDE + pos] = ((unsigned)(d & 255) << 17) | (unsigned)s;
    }
  }
}

// ---- pass 2: per-partition bucket build in LDS, coalesced writeout ------------
// Also emits cnt and dinv (merges old k_dinv).
__global__ __launch_bounds__(256) void k_part2(const unsigned* __restrict__ pdata,
                                               const int* __restrict__ pcnt,
                                               unsigned short* __restrict__ bucket,
                                               int* __restrict__ cnt,
                                               float* __restrict__ dinv, int n) {
  __shared__ unsigned short lb[256][CAP];
  __shared__ int lc[256];
  const int t = threadIdx.x;
  const int p = blockIdx.x;
  lc[t] = 0;
  __syncthreads();
  const int m = min(pcnt[p], PSTRIDE);
  for (int i = t; i < m; i += 256) {
    unsigned u = pdata[(size_t)p * PSTRIDE + i];
    int dl = u >> 17;
    int pos = atomicAdd(&lc[dl], 1);
    if (pos < CAP) lb[dl][pos] = (unsigned short)(u & 0x1FFFFu);
  }
  __syncthreads();
  int node = p * 256 + t;
  if (node < n) {
    int c = lc[t];
    cnt[node] = c;
    dinv[node] = rsqrtf((float)(c + 1));
  }
  // flat coalesced copy LDS -> global (256 rows x 128B)
  unsigned* bw = (unsigned*)(bucket + (size_t)p * 256 * CAP);
  const unsigned* ls = (const unsigned*)lb;
  for (int f = t; f < 256 * (CAP / 2); f += 256) bw[f] = ls[f];
}

// ---- aggvec: outv[i] = dinv[i] * (in[i] + sum_{src in in(i)} in[src]) --------
__global__ __launch_bounds__(256) void k_aggvec(const float* __restrict__ in,
                                                float* __restrict__ outv,
                                                const unsigned short* __restrict__ bucket,
                                                const int* __restrict__ cnt,
                                                const float* __restrict__ dinv,
                                                int n) {
  int wid = (blockIdx.x * 256 + threadIdx.x) >> 6;
  int lane = threadIdx.x & 63;
  if (wid >= n) return;
  int c = min(cnt[wid], CAP);
  float v = 0.f;
  if (lane < c) v = in[bucket[(size_t)wid * CAP + lane]];
#pragma unroll
  for (int off = 32; off; off >>= 1) v += __shfl_xor(v, off);
  if (lane == 0) outv[wid] = dinv[wid] * (in[wid] + v);
}

// ---------------- tiny f32 matmul: C[M][N] = A[M][K] @ B[K][N] ----------------
__global__ __launch_bounds__(256) void k_mm_f32(const float* __restrict__ A,
                                                const float* __restrict__ B,
                                                float* __restrict__ C,
                                                int M, int K, int N) {
  int i = blockIdx.x * 256 + threadIdx.x;
  if (i >= M * N) return;
  int r = i / N, c = i - r * N;
  float s = 0.f;
  for (int k = 0; k < K; ++k) s += A[(size_t)r * K + k] * B[(size_t)k * N + c];
  C[i] = s;
}

// ---- split W123[K=256][40] -> bf16 hi/lo transposed+padded [48][256] ---------
__global__ __launch_bounds__(256) void k_wsplit_t(const float* __restrict__ W,
                                                  unsigned short* __restrict__ Wh,
                                                  unsigned short* __restrict__ Wl) {
  int i = blockIdx.x * 256 + threadIdx.x;
  if (i >= 48 * 256) return;
  int c = i >> 8, k = i & 255;
  float x = (c < 40) ? W[(size_t)k * 40 + c] : 0.f;
  unsigned short h = f2bf(x);
  unsigned short l = f2bf(x - bf2f(h));
  Wh[i] = h;
  Wl[i] = l;
}

// ---- bias prep: v1 = b1^T W2 W3 (40), v2 = b2^T W3 (40) ----------------------
__global__ __launch_bounds__(256) void k_bias_prep(const float* __restrict__ b1,
                                                   const float* __restrict__ W2,
                                                   const float* __restrict__ W3,
                                                   const float* __restrict__ b2,
                                                   float* __restrict__ v1,
                                                   float* __restrict__ v2) {
  __shared__ float w2b[128];
  int t = threadIdx.x;
  if (t < 128) {
    float s = 0.f;
    for (int k = 0; k < 128; ++k) s += b1[k] * W2[(size_t)k * 128 + t];
    w2b[t] = s;
  }
  __syncthreads();
  if (t < 40) {
    float s1 = 0.f, s2 = 0.f;
    for (int j = 0; j < 128; ++j) {
      float w = W3[(size_t)j * 40 + t];
      s1 += w2b[j] * w;
      s2 += b2[j] * w;
    }
    v1[t] = s1;
    v2[t] = s2;
  }
}

// ---- MFMA split-bf16 GEMM: Z[M][40] = dinv[row] * (X[M][256] @ W123) ---------
__global__ __launch_bounds__(256, 2) void k_zgemm(const float* __restrict__ X,
                                                  const unsigned short* __restrict__ Bhg,
                                                  const unsigned short* __restrict__ Blg,
                                                  const float* __restrict__ dinv,
                                                  float* __restrict__ Z, int M) {
  __shared__ unsigned short Ah[64][72], Al[64][72];  // [row][k]
  __shared__ unsigned short Bh[48][72], Bl[48][72];  // [col][k]
  const int t = threadIdx.x;
  const int bm = blockIdx.x * 64;
  const int wv = t >> 6, la = t & 63;
  const int ra = la & 15;  // row/col within 16x16 frag
  const int rq = la >> 4;  // k-group 0..3

  f32x4 acc[3];
#pragma unroll
  for (int j = 0; j < 3; ++j) acc[j] = (f32x4){0.f, 0.f, 0.f, 0.f};

  for (int k0 = 0; k0 < 256; k0 += 64) {
#pragma unroll
    for (int l = 0; l < 4; ++l) {
      int idx = l * 256 + t;
      int r = idx >> 4, c4 = (idx & 15) * 4;
      int gr = bm + r;
      float4 v = make_float4(0.f, 0.f, 0.f, 0.f);
      if (gr < M) v = *(const float4*)(X + (size_t)gr * 256 + k0 + c4);
      unsigned short h0 = f2bf(v.x), h1 = f2bf(v.y), h2 = f2bf(v.z), h3 = f2bf(v.w);
      unsigned short q0 = f2bf(v.x - bf2f(h0)), q1 = f2bf(v.y - bf2f(h1));
      unsigned short q2 = f2bf(v.z - bf2f(h2)), q3 = f2bf(v.w - bf2f(h3));
      *(ushort4*)&Ah[r][c4] = make_ushort4(h0, h1, h2, h3);
      *(ushort4*)&Al[r][c4] = make_ushort4(q0, q1, q2, q3);
    }
#pragma unroll
    for (int l = 0; l < 2; ++l) {
      int idx = l * 256 + t;
      if (idx < 48 * 8) {
        int c = idx >> 3, k8 = (idx & 7) * 8;
        *(bf16x8*)&Bh[c][k8] = *(const bf16x8*)(Bhg + (size_t)c * 256 + k0 + k8);
        *(bf16x8*)&Bl[c][k8] = *(const bf16x8*)(Blg + (size_t)c * 256 + k0 + k8);
      }
    }
    __syncthreads();
#pragma unroll
    for (int ks = 0; ks < 2; ++ks) {
      const int ko = ks * 32 + rq * 8;
      bf16x8 a_h = *(const bf16x8*)&Ah[wv * 16 + ra][ko];
      bf16x8 a_l = *(const bf16x8*)&Al[wv * 16 + ra][ko];
#pragma unroll
      for (int j = 0; j < 3; ++j) {
        bf16x8 b_h = *(const bf16x8*)&Bh[j * 16 + ra][ko];
        bf16x8 b_l = *(const bf16x8*)&Bl[j * 16 + ra][ko];
        acc[j] = __builtin_amdgcn_mfma_f32_16x16x32_bf16(a_h, b_h, acc[j], 0, 0, 0);
        acc[j] = __builtin_amdgcn_mfma_f32_16x16x32_bf16(a_h, b_l, acc[j], 0, 0, 0);
        acc[j] = __builtin_amdgcn_mfma_f32_16x16x32_bf16(a_l, b_h, acc[j], 0, 0, 0);
      }
    }
    __syncthreads();
  }
  // D layout: col = la&15, row = (la>>4)*4 + r  [m89-verified]
#pragma unroll
  for (int j = 0; j < 3; ++j)
#pragma unroll
    for (int r = 0; r < 4; ++r) {
      int row = bm + wv * 16 + rq * 4 + r;
      int col = j * 16 + ra;
      if (row < M && col < 40)
        Z[(size_t)row * 40 + col] = acc[j][r] * dinv[row];
    }
}

// ---- aggregation pass, F=40 (wave per node, unroll 8) ------------------------
// FINAL=0: out = dinv^2 * s ; FINAL=1: out = dinv*s + u2*v1 + u1*v2 + b3
template <int FINAL>
__global__ __launch_bounds__(256) void k_agg40x(const float* __restrict__ in,
                                                float* __restrict__ out,
                                                const unsigned short* __restrict__ bucket,
                                                const int* __restrict__ cnt,
                                                const float* __restrict__ dinv,
                                                const float* __restrict__ u1,
                                                const float* __restrict__ u2,
                                                const float* __restrict__ v1,
                                                const float* __restrict__ v2,
                                                const float* __restrict__ b3,
                                                int n) {
  int wid = (blockIdx.x * 256 + threadIdx.x) >> 6;
  int lane = threadIdx.x & 63;
  if (wid >= n) return;
  int le = lane < 40 ? lane : 0;
  int c = min(cnt[wid], CAP);
  float di = dinv[wid];
  int idx = (lane < c) ? (int)bucket[(size_t)wid * CAP + lane] : 0;
  float a[8];
  a[0] = in[(size_t)wid * 40 + le];  // self loop
#pragma unroll
  for (int u = 1; u < 8; ++u) a[u] = 0.f;
  for (int e = 0; e < c; e += 8) {
#pragma unroll
    for (int u = 0; u < 8; ++u) {
      int valid = (e + u) < c;
      int s = __shfl(idx, e + u);
      s = valid ? s : wid;
      float m = valid ? 1.f : 0.f;
      a[u] = fmaf(in[(size_t)s * 40 + le], m, a[u]);
    }
  }
  float sa = ((a[0] + a[1]) + (a[2] + a[3])) + ((a[4] + a[5]) + (a[6] + a[7]));
  if (lane < 40) {
    if (FINAL) {
      out[(size_t)wid * 40 + lane] =
          sa * di + u2[wid] * v1[lane] + u1[wid] * v2[lane] + b3[lane];
    } else {
      out[(size_t)wid * 40 + lane] = sa * di * di;
    }
  }
}

extern "C" void kernel_launch(void* const* d_in, const int* in_sizes, int n_in,
                              void* d_out, int out_size, void* d_ws, size_t ws_size,
                              hipStream_t stream) {
  const float* x  = (const float*)d_in[0];
  const int*   ei = (const int*)d_in[1];
  const float* W1 = (const float*)d_in[2];
  const float* b1 = (const float*)d_in[3];
  const float* W2 = (const float*)d_in[4];
  const float* b2 = (const float*)d_in[5];
  const float* W3 = (const float*)d_in[6];
  const float* b3 = (const float*)d_in[7];
  float* out = (float*)d_out;

  const int n = in_sizes[0] / 256;  // 50000
  const int E = in_sizes[1] / 2;    // 800000

  char* ws = (char*)d_ws;
  int*   cnt    = (int*)(ws + 0);                        // 200 KB
  float* dinv   = (float*)(ws + (1ll << 20));            // 200 KB
  unsigned short* bucket = (unsigned short*)(ws + (2ll << 20));  // 6.42 MB (50176 rows)
  int*   pcnt   = (int*)(ws + (9ll << 20));              // 784 B
  unsigned* pdata = (unsigned*)(ws + (10ll << 20));      // 3.6 MB
  float* u1     = (float*)(ws + (15ll << 20));           // 200 KB
  float* u2     = (float*)(ws + (15ll << 20) + (256 << 10));
  float* W12    = (float*)(ws + (15ll << 20) + (512 << 10));  // 128 KB
  float* W123   = (float*)(ws + (15ll << 20) + (704 << 10));  // 40 KB
  unsigned short* Wh = (unsigned short*)(ws + (15ll << 20) + (768 << 10));  // 24 KB
  unsigned short* Wl = (unsigned short*)(ws + (15ll << 20) + (800 << 10));  // 24 KB
  float* v1     = (float*)(ws + (15ll << 20) + (832 << 10));
  float* v2     = (float*)(ws + (15ll << 20) + (836 << 10));
  float* bufA   = (float*)(ws + (16ll << 20));           // 8 MB
  float* bufB   = (float*)(ws + (26ll << 20));           // 8 MB

  // two-phase bucket build (partitioned, coalesced; also computes cnt+dinv)
  hipMemsetAsync(pcnt, 0, NPART * sizeof(int), stream);
  k_part1<<<(E + 4095) / 4096, 256, 0, stream>>>(ei, pcnt, pdata, E);
  k_part2<<<NPART, 256, 0, stream>>>(pdata, pcnt, bucket, cnt, dinv, n);

  int ab = (n * 64 + 255) / 256;  // one wave per node
  // u1 = S*1, u2 = S^2*1
  k_aggvec<<<ab, 256, 0, stream>>>(dinv, u1, bucket, cnt, dinv, n);
  k_aggvec<<<ab, 256, 0, stream>>>(u1, u2, bucket, cnt, dinv, n);

  // W123 = W1@W2@W3; split to bf16 hi/lo transposed [48][256]
  k_mm_f32<<<(256 * 128 + 255) / 256, 256, 0, stream>>>(W1, W2, W12, 256, 128, 128);
  k_mm_f32<<<(256 * 40 + 255) / 256, 256, 0, stream>>>(W12, W3, W123, 256, 128, 40);
  k_wsplit_t<<<(48 * 256 + 255) / 256, 256, 0, stream>>>(W123, Wh, Wl);
  k_bias_prep<<<1, 256, 0, stream>>>(b1, W2, W3, b2, v1, v2);

  // Z = dinv * (X @ W123)
  k_zgemm<<<(n + 63) / 64, 256, 0, stream>>>(x, Wh, Wl, dinv, bufA, n);

  // out = S^3 Z + u2 v1^T + u1 v2^T + 1 b3^T
  k_agg40x<0><<<ab, 256, 0, stream>>>(bufA, bufB, bucket, cnt, dinv, u1, u2, v1, v2, b3, n);
  k_agg40x<0><<<ab, 256, 0, stream>>>(bufB, bufA, bucket, cnt, dinv, u1, u2, v1, v2, b3, n);
  k_agg40x<1><<<ab, 256, 0, stream>>>(bufA, out, bucket, cnt, dinv, u1, u2, v1, v2, b3, n);
}

// Round 9
// 156.140 us; speedup vs baseline: 2.2099x; 1.3764x over previous
//
#include <hip/hip_runtime.h>
#include <math.h>

#define CAP 64      // bucket capacity per node; Poisson(16) max ~45 whp
#define NPART 196   // ceil(50000/256) partitions of 256 dst nodes
#define PSTRIDE 4608  // per-partition edge capacity (mean 4096 + 8 sigma)

typedef __attribute__((ext_vector_type(8))) short bf16x8;
typedef __attribute__((ext_vector_type(4))) float f32x4;

__device__ __forceinline__ unsigned short f2bf(float x) {  // RTN-even f32->bf16
  unsigned u = __float_as_uint(x);
  return (unsigned short)((u + 0x7fffu + ((u >> 16) & 1u)) >> 16);
}
__device__ __forceinline__ float bf2f(unsigned short h) {
  return __uint_as_float(((unsigned)h) << 16);
}

__global__ __launch_bounds__(256) void k_zero(int* __restrict__ pcnt) {
  if (threadIdx.x < NPART) pcnt[threadIdx.x] = 0;
}

// ---- pass 1: partition edges by dst>>8, packed (dstlow<<17)|src ---------------
__global__ __launch_bounds__(256) void k_part1(const int* __restrict__ ei,
                                               int* __restrict__ pcnt,
                                               unsigned* __restrict__ pdata, int E) {
  __shared__ int gc[NPART];
  __shared__ int gb[NPART];
  const int t = threadIdx.x;
  const int base = blockIdx.x * 4096;
  for (int i = t; i < NPART; i += 256) gc[i] = 0;
  __syncthreads();
#pragma unroll 4
  for (int l = 0; l < 16; ++l) {
    int e = base + l * 256 + t;
    if (e < E) atomicAdd(&gc[ei[E + e] >> 8], 1);
  }
  __syncthreads();
  for (int i = t; i < NPART; i += 256) {
    gb[i] = atomicAdd(&pcnt[i], gc[i]);  // reserve contiguous range
    gc[i] = 0;
  }
  __syncthreads();
#pragma unroll 4
  for (int l = 0; l < 16; ++l) {
    int e = base + l * 256 + t;
    if (e < E) {
      int d = ei[E + e];
      int s = ei[e];
      int g = d >> 8;
      int pos = gb[g] + atomicAdd(&gc[g], 1);
      if (pos < PSTRIDE)
        pdata[(size_t)g * PSTRIDE + pos] = ((unsigned)(d & 255) << 17) | (unsigned)s;
    }
  }
}

// ---- pass 2: per-partition bucket build in LDS, coalesced writeout ------------
__global__ __launch_bounds__(256) void k_part2(const unsigned* __restrict__ pdata,
                                               const int* __restrict__ pcnt,
                                               unsigned short* __restrict__ bucket,
                                               int* __restrict__ cnt,
                                               float* __restrict__ dinv, int n) {
  __shared__ unsigned short lb[256][CAP];
  __shared__ int lc[256];
  const int t = threadIdx.x;
  const int p = blockIdx.x;
  lc[t] = 0;
  __syncthreads();
  const int m = min(pcnt[p], PSTRIDE);
  for (int i = t; i < m; i += 256) {
    unsigned u = pdata[(size_t)p * PSTRIDE + i];
    int dl = u >> 17;
    int pos = atomicAdd(&lc[dl], 1);
    if (pos < CAP) lb[dl][pos] = (unsigned short)(u & 0x1FFFFu);
  }
  __syncthreads();
  int node = p * 256 + t;
  if (node < n) {
    int c = lc[t];
    cnt[node] = c;
    dinv[node] = rsqrtf((float)(c + 1));
  }
  unsigned* bw = (unsigned*)(bucket + (size_t)p * 256 * CAP);
  const unsigned* ls = (const unsigned*)lb;
  for (int f = t; f < 256 * (CAP / 2); f += 256) bw[f] = ls[f];
}

// ---- aggvec: outv[i] = dinv[i] * (in[i] + sum_{src in in(i)} in[src]) --------
__global__ __launch_bounds__(256) void k_aggvec(const float* __restrict__ in,
                                                float* __restrict__ outv,
                                                const unsigned short* __restrict__ bucket,
                                                const int* __restrict__ cnt,
                                                const float* __restrict__ dinv,
                                                int n) {
  int wid = (blockIdx.x * 256 + threadIdx.x) >> 6;
  int lane = threadIdx.x & 63;
  if (wid >= n) return;
  int c = min(cnt[wid], CAP);
  float v = 0.f;
  if (lane < c) v = in[bucket[(size_t)wid * CAP + lane]];
#pragma unroll
  for (int off = 32; off; off >>= 1) v += __shfl_xor(v, off);
  if (lane == 0) outv[wid] = dinv[wid] * (in[wid] + v);
}

// ---- small matmul with bias row: C[M][N] = A[M][K]@B[K][N]; vout = bvec^T B ---
// 4 independent accumulators break the serial FMA chain (ILP x4).
template <int K>
__global__ __launch_bounds__(256) void k_mm40(const float* __restrict__ A,
                                              const float* __restrict__ bvec,
                                              const float* __restrict__ B,
                                              float* __restrict__ C,
                                              float* __restrict__ vout,
                                              int M, int N) {
  int i = blockIdx.x * 256 + threadIdx.x;
  if (i >= (M + 1) * N) return;
  int r = i / N, c = i - r * N;
  const float* a = (r < M) ? (A + (size_t)r * K) : bvec;
  float s0 = 0.f, s1 = 0.f, s2 = 0.f, s3 = 0.f;
#pragma unroll 4
  for (int k = 0; k < K; k += 4) {
    s0 += a[k + 0] * B[(size_t)(k + 0) * N + c];
    s1 += a[k + 1] * B[(size_t)(k + 1) * N + c];
    s2 += a[k + 2] * B[(size_t)(k + 2) * N + c];
    s3 += a[k + 3] * B[(size_t)(k + 3) * N + c];
  }
  float s = (s0 + s1) + (s2 + s3);
  if (r < M) C[(size_t)r * N + c] = s;
  else vout[c] = s;
}

// ---- split W123[K=256][40] -> bf16 hi/lo transposed+padded [48][256] ---------
__global__ __launch_bounds__(256) void k_wsplit_t(const float* __restrict__ W,
                                                  unsigned short* __restrict__ Wh,
                                                  unsigned short* __restrict__ Wl) {
  int i = blockIdx.x * 256 + threadIdx.x;
  if (i >= 48 * 256) return;
  int c = i >> 8, k = i & 255;
  float x = (c < 40) ? W[(size_t)k * 40 + c] : 0.f;
  unsigned short h = f2bf(x);
  unsigned short l = f2bf(x - bf2f(h));
  Wh[i] = h;
  Wl[i] = l;
}

// ---- MFMA split-bf16 GEMM: Z[M][40] = dinv[row] * (X[M][256] @ W123) ---------
__global__ __launch_bounds__(256, 2) void k_zgemm(const float* __restrict__ X,
                                                  const unsigned short* __restrict__ Bhg,
                                                  const unsigned short* __restrict__ Blg,
                                                  const float* __restrict__ dinv,
                                                  float* __restrict__ Z, int M) {
  __shared__ unsigned short Ah[64][72], Al[64][72];  // [row][k]
  __shared__ unsigned short Bh[48][72], Bl[48][72];  // [col][k]
  const int t = threadIdx.x;
  const int bm = blockIdx.x * 64;
  const int wv = t >> 6, la = t & 63;
  const int ra = la & 15;  // row/col within 16x16 frag
  const int rq = la >> 4;  // k-group 0..3

  f32x4 acc[3];
#pragma unroll
  for (int j = 0; j < 3; ++j) acc[j] = (f32x4){0.f, 0.f, 0.f, 0.f};

  for (int k0 = 0; k0 < 256; k0 += 64) {
#pragma unroll
    for (int l = 0; l < 4; ++l) {
      int idx = l * 256 + t;
      int r = idx >> 4, c4 = (idx & 15) * 4;
      int gr = bm + r;
      float4 v = make_float4(0.f, 0.f, 0.f, 0.f);
      if (gr < M) v = *(const float4*)(X + (size_t)gr * 256 + k0 + c4);
      unsigned short h0 = f2bf(v.x), h1 = f2bf(v.y), h2 = f2bf(v.z), h3 = f2bf(v.w);
      unsigned short q0 = f2bf(v.x - bf2f(h0)), q1 = f2bf(v.y - bf2f(h1));
      unsigned short q2 = f2bf(v.z - bf2f(h2)), q3 = f2bf(v.w - bf2f(h3));
      *(ushort4*)&Ah[r][c4] = make_ushort4(h0, h1, h2, h3);
      *(ushort4*)&Al[r][c4] = make_ushort4(q0, q1, q2, q3);
    }
#pragma unroll
    for (int l = 0; l < 2; ++l) {
      int idx = l * 256 + t;
      if (idx < 48 * 8) {
        int c = idx >> 3, k8 = (idx & 7) * 8;
        *(bf16x8*)&Bh[c][k8] = *(const bf16x8*)(Bhg + (size_t)c * 256 + k0 + k8);
        *(bf16x8*)&Bl[c][k8] = *(const bf16x8*)(Blg + (size_t)c * 256 + k0 + k8);
      }
    }
    __syncthreads();
#pragma unroll
    for (int ks = 0; ks < 2; ++ks) {
      const int ko = ks * 32 + rq * 8;
      bf16x8 a_h = *(const bf16x8*)&Ah[wv * 16 + ra][ko];
      bf16x8 a_l = *(const bf16x8*)&Al[wv * 16 + ra][ko];
#pragma unroll
      for (int j = 0; j < 3; ++j) {
        bf16x8 b_h = *(const bf16x8*)&Bh[j * 16 + ra][ko];
        bf16x8 b_l = *(const bf16x8*)&Bl[j * 16 + ra][ko];
        acc[j] = __builtin_amdgcn_mfma_f32_16x16x32_bf16(a_h, b_h, acc[j], 0, 0, 0);
        acc[j] = __builtin_amdgcn_mfma_f32_16x16x32_bf16(a_h, b_l, acc[j], 0, 0, 0);
        acc[j] = __builtin_amdgcn_mfma_f32_16x16x32_bf16(a_l, b_h, acc[j], 0, 0, 0);
      }
    }
    __syncthreads();
  }
  // D layout: col = la&15, row = (la>>4)*4 + r  [m89-verified]
#pragma unroll
  for (int j = 0; j < 3; ++j)
#pragma unroll
    for (int r = 0; r < 4; ++r) {
      int row = bm + wv * 16 + rq * 4 + r;
      int col = j * 16 + ra;
      if (row < M && col < 40)
        Z[(size_t)row * 40 + col] = acc[j][r] * dinv[row];
    }
}

// ---- aggregation pass, F=40 (wave per node, unroll 8) ------------------------
// FINAL=0: out = dinv^2 * s ; FINAL=1: out = dinv*s + u2*v1 + u1*v2 + b3
template <int FINAL>
__global__ __launch_bounds__(256) void k_agg40x(const float* __restrict__ in,
                                                float* __restrict__ out,
                                                const unsigned short* __restrict__ bucket,
                                                const int* __restrict__ cnt,
                                                const float* __restrict__ dinv,
                                                const float* __restrict__ u1,
                                                const float* __restrict__ u2,
                                                const float* __restrict__ v1,
                                                const float* __restrict__ v2,
                                                const float* __restrict__ b3,
                                                int n) {
  int wid = (blockIdx.x * 256 + threadIdx.x) >> 6;
  int lane = threadIdx.x & 63;
  if (wid >= n) return;
  int le = lane < 40 ? lane : 0;
  int c = min(cnt[wid], CAP);
  float di = dinv[wid];
  int idx = (lane < c) ? (int)bucket[(size_t)wid * CAP + lane] : 0;
  float a[8];
  a[0] = in[(size_t)wid * 40 + le];  // self loop
#pragma unroll
  for (int u = 1; u < 8; ++u) a[u] = 0.f;
  for (int e = 0; e < c; e += 8) {
#pragma unroll
    for (int u = 0; u < 8; ++u) {
      int valid = (e + u) < c;
      int s = __shfl(idx, e + u);
      s = valid ? s : wid;
      float m = valid ? 1.f : 0.f;
      a[u] = fmaf(in[(size_t)s * 40 + le], m, a[u]);
    }
  }
  float sa = ((a[0] + a[1]) + (a[2] + a[3])) + ((a[4] + a[5]) + (a[6] + a[7]));
  if (lane < 40) {
    if (FINAL) {
      out[(size_t)wid * 40 + lane] =
          sa * di + u2[wid] * v1[lane] + u1[wid] * v2[lane] + b3[lane];
    } else {
      out[(size_t)wid * 40 + lane] = sa * di * di;
    }
  }
}

extern "C" void kernel_launch(void* const* d_in, const int* in_sizes, int n_in,
                              void* d_out, int out_size, void* d_ws, size_t ws_size,
                              hipStream_t stream) {
  const float* x  = (const float*)d_in[0];
  const int*   ei = (const int*)d_in[1];
  const float* W1 = (const float*)d_in[2];
  const float* b1 = (const float*)d_in[3];
  const float* W2 = (const float*)d_in[4];
  const float* b2 = (const float*)d_in[5];
  const float* W3 = (const float*)d_in[6];
  const float* b3 = (const float*)d_in[7];
  float* out = (float*)d_out;

  const int n = in_sizes[0] / 256;  // 50000
  const int E = in_sizes[1] / 2;    // 800000

  char* ws = (char*)d_ws;
  int*   cnt    = (int*)(ws + 0);                        // 200 KB
  float* dinv   = (float*)(ws + (1ll << 20));            // 200 KB
  unsigned short* bucket = (unsigned short*)(ws + (2ll << 20));  // 6.42 MB
  int*   pcnt   = (int*)(ws + (9ll << 20));              // 784 B
  unsigned* pdata = (unsigned*)(ws + (10ll << 20));      // 3.6 MB
  float* u1     = (float*)(ws + (15ll << 20));           // 200 KB
  float* u2     = (float*)(ws + (15ll << 20) + (256 << 10));
  float* W23    = (float*)(ws + (15ll << 20) + (512 << 10));  // 20 KB
  float* W123   = (float*)(ws + (15ll << 20) + (704 << 10));  // 40 KB
  unsigned short* Wh = (unsigned short*)(ws + (15ll << 20) + (768 << 10));  // 24 KB
  unsigned short* Wl = (unsigned short*)(ws + (15ll << 20) + (800 << 10));  // 24 KB
  float* v1     = (float*)(ws + (15ll << 20) + (832 << 10));
  float* v2     = (float*)(ws + (15ll << 20) + (836 << 10));
  float* bufA   = (float*)(ws + (16ll << 20));           // 8 MB
  float* bufB   = (float*)(ws + (26ll << 20));           // 8 MB

  // two-phase bucket build (partitioned, coalesced; also computes cnt+dinv)
  k_zero<<<1, 256, 0, stream>>>(pcnt);
  k_part1<<<(E + 4095) / 4096, 256, 0, stream>>>(ei, pcnt, pdata, E);
  k_part2<<<NPART, 256, 0, stream>>>(pdata, pcnt, bucket, cnt, dinv, n);

  int ab = (n * 64 + 255) / 256;  // one wave per node
  // u1 = S*1, u2 = S^2*1
  k_aggvec<<<ab, 256, 0, stream>>>(dinv, u1, bucket, cnt, dinv, n);
  k_aggvec<<<ab, 256, 0, stream>>>(u1, u2, bucket, cnt, dinv, n);

  // W23 = W2@W3 (+ v2 = b2^T W3); W123 = W1@W23 (+ v1 = b1^T W23); split bf16
  k_mm40<128><<<(129 * 40 + 255) / 256, 256, 0, stream>>>(W2, b2, W3, W23, v2, 128, 40);
  k_mm40<128><<<(257 * 40 + 255) / 256, 256, 0, stream>>>(W1, b1, W23, W123, v1, 256, 40);
  k_wsplit_t<<<(48 * 256 + 255) / 256, 256, 0, stream>>>(W123, Wh, Wl);

  // Z = dinv * (X @ W123)
  k_zgemm<<<(n + 63) / 64, 256, 0, stream>>>(x, Wh, Wl, dinv, bufA, n);

  // out = S^3 Z + u2 v1^T + u1 v2^T + 1 b3^T
  k_agg40x<0><<<ab, 256, 0, stream>>>(bufA, bufB, bucket, cnt, dinv, u1, u2, v1, v2, b3, n);
  k_agg40x<0><<<ab, 256, 0, stream>>>(bufB, bufA, bucket, cnt, dinv, u1, u2, v1, v2, b3, n);
  k_agg40x<1><<<ab, 256, 0, stream>>>(bufA, out, bucket, cnt, dinv, u1, u2, v1, v2, b3, n);
}